// Round 1
// baseline (384.390 us; speedup 1.0000x reference)
//
#include <hip/hip_runtime.h>

#define HW   9216
#define IMG  96
#define NB   8
#define NK   4

typedef __bf16 bf16x8 __attribute__((ext_vector_type(8)));
typedef float  f32x4  __attribute__((ext_vector_type(4)));

__device__ __forceinline__ unsigned short f2bf(float f) {
    unsigned int u = __float_as_uint(f);
    u += 0x7FFFu + ((u >> 16) & 1u);   // round-to-nearest-even (finite inputs)
    return (unsigned short)(u >> 16);
}
__device__ __forceinline__ float bf2f(unsigned short h) {
    return __uint_as_float(((unsigned int)h) << 16);
}

// ---------------------------------------------------------------------------
// Kernel 1: per-pixel prep.
//   - transpose-convert x [b][c][hw] fp32 -> xbt [b][hw][c] bf16 (GEMM B-operand layout)
//   - 12 dot products/pixel: flows (K*2) and softmax logits (K), fp32 exact
//   - writes sample coords (ix,iy) [k][b][hw] and softmax weights [k][b][hw]
// block: 256 thr, 128 pixels; grid: 8*72
// ---------------------------------------------------------------------------
extern "C" __global__ __launch_bounds__(256)
void prep_kernel(const float* __restrict__ x,
                 const float* __restrict__ Woff,
                 const float* __restrict__ boff,
                 const float* __restrict__ Wwt,
                 const float* __restrict__ bwt,
                 unsigned short* __restrict__ xbt,
                 float2* __restrict__ coords,
                 float* __restrict__ wts)
{
    __shared__ float tile[32 * 128];
    const int t  = threadIdx.x;
    const int bx = blockIdx.x;
    const int b  = bx / 72;
    const int p0 = (bx % 72) * 128;

    const int setid = __builtin_amdgcn_readfirstlane(t >> 7);  // wave-uniform 0/1
    const int pl = t & 127;

    // 6 weight rows per set, uniform pointers -> scalar loads
    const float* rows[6];
    if (setid == 0) {
        #pragma unroll
        for (int j = 0; j < 6; ++j) rows[j] = Woff + j * 256;
    } else {
        rows[0] = Woff + 6 * 256;
        rows[1] = Woff + 7 * 256;
        #pragma unroll
        for (int j = 0; j < 4; ++j) rows[2 + j] = Wwt + j * 256;
    }

    float acc[6] = {0.f, 0.f, 0.f, 0.f, 0.f, 0.f};

    for (int c0 = 0; c0 < 256; c0 += 32) {
        __syncthreads();
        // stage 32c x 128p fp32 chunk (coalesced float4)
        const float* src = x + ((size_t)(b * 256 + c0)) * HW + p0;
        #pragma unroll
        for (int i = 0; i < 4; ++i) {
            int u = t + 256 * i;
            int r = u >> 5, q = u & 31;
            float4 v = *(const float4*)(src + (size_t)r * HW + q * 4);
            *(float4*)(tile + r * 128 + q * 4) = v;
        }
        __syncthreads();
        // transposed bf16 write: [p][c] with 8 contiguous c per 16B store
        #pragma unroll
        for (int i = 0; i < 2; ++i) {
            int u = t + 256 * i;             // 0..511 = 128p x 4sub
            int sub = u & 3, p = u >> 2;
            union { unsigned short h[8]; int4 v; } pk;
            #pragma unroll
            for (int j = 0; j < 8; ++j)
                pk.h[j] = f2bf(tile[(sub * 8 + j) * 128 + p]);
            *(int4*)(xbt + ((size_t)b * HW + p0 + p) * 256 + c0 + sub * 8) = pk.v;
        }
        // dot accumulation: thread owns pixel pl, 6 outputs of its set
        for (int cc = 0; cc < 32; ++cc) {
            float xv = tile[cc * 128 + pl];
            int c = c0 + cc;
            #pragma unroll
            for (int j = 0; j < 6; ++j)
                acc[j] += xv * rows[j][c];
        }
    }

    const int p = p0 + pl;
    const float py = (float)(p / IMG);
    const float px = (float)(p % IMG);

    if (setid == 0) {
        // flows k = 0,1,2
        #pragma unroll
        for (int k = 0; k < 3; ++k) {
            float fx = acc[k * 2 + 0] + boff[k * 2 + 0];
            float fy = acc[k * 2 + 1] + boff[k * 2 + 1];
            float vx = 2.0f * (px + fx) / 95.0f - 1.0f;
            float vy = 2.0f * (py + fy) / 95.0f - 1.0f;
            float ix = (vx + 1.0f) * 48.0f - 0.5f;
            float iy = (vy + 1.0f) * 48.0f - 0.5f;
            coords[((size_t)k * NB + b) * HW + p] = make_float2(ix, iy);
        }
    } else {
        // flow k = 3
        {
            float fx = acc[0] + boff[6];
            float fy = acc[1] + boff[7];
            float vx = 2.0f * (px + fx) / 95.0f - 1.0f;
            float vy = 2.0f * (py + fy) / 95.0f - 1.0f;
            float ix = (vx + 1.0f) * 48.0f - 0.5f;
            float iy = (vy + 1.0f) * 48.0f - 0.5f;
            coords[((size_t)3 * NB + b) * HW + p] = make_float2(ix, iy);
        }
        // softmax over 4 logits
        float l0 = acc[2] + bwt[0];
        float l1 = acc[3] + bwt[1];
        float l2 = acc[4] + bwt[2];
        float l3 = acc[5] + bwt[3];
        float m = fmaxf(fmaxf(l0, l1), fmaxf(l2, l3));
        float e0 = __expf(l0 - m), e1 = __expf(l1 - m);
        float e2 = __expf(l2 - m), e3 = __expf(l3 - m);
        float inv = 1.0f / (e0 + e1 + e2 + e3);
        wts[((size_t)0 * NB + b) * HW + p] = e0 * inv;
        wts[((size_t)1 * NB + b) * HW + p] = e1 * inv;
        wts[((size_t)2 * NB + b) * HW + p] = e2 * inv;
        wts[((size_t)3 * NB + b) * HW + p] = e3 * inv;
    }
}

// ---------------------------------------------------------------------------
// Kernel 2: Wc fp32 -> bf16 (row-major [o][c], the A-operand layout)
// ---------------------------------------------------------------------------
extern "C" __global__ __launch_bounds__(256)
void wcconv_kernel(const float* __restrict__ Wc, unsigned short* __restrict__ Wcb)
{
    int u = (blockIdx.x * 256 + threadIdx.x) * 4;
    float4 v = *(const float4*)(Wc + u);
    union { unsigned short h[4]; int2 p; } pk;
    pk.h[0] = f2bf(v.x); pk.h[1] = f2bf(v.y);
    pk.h[2] = f2bf(v.z); pk.h[3] = f2bf(v.w);
    *(int2*)(Wcb + u) = pk.p;
}

// ---------------------------------------------------------------------------
// Kernel 3: bf16 MFMA GEMM per batch: proj[b][o][p] = sum_c Wc[o][c]*x[b][c][p] + bc[o]
//   A = Wcb [o][c] row-major, B = xbt[b] [p][c] row-major (both k-contiguous).
//   128x128 tile, BK=32, 4 waves x (4x4 of 16x16x32). grid: 8b x 2m x 72n
// ---------------------------------------------------------------------------
extern "C" __global__ __launch_bounds__(256)
void gemm_kernel(const unsigned short* __restrict__ Wcb,
                 const unsigned short* __restrict__ xbt,
                 const float* __restrict__ bc,
                 unsigned short* __restrict__ proj)
{
    __shared__ __align__(16) unsigned short As[128 * 32];
    __shared__ __align__(16) unsigned short Bs[128 * 32];

    const int t  = threadIdx.x;
    const int bx = blockIdx.x;
    const int b  = bx / 144;
    const int r  = bx % 144;
    const int m0 = (r / 72) * 128;   // o tile
    const int p0 = (r % 72) * 128;   // p tile

    const int lane = t & 63, wave = t >> 6;
    const int wm = (wave >> 1) * 64, wn = (wave & 1) * 64;
    const int l15 = lane & 15, quad = lane >> 4;

    f32x4 acc[4][4];
    #pragma unroll
    for (int mt = 0; mt < 4; ++mt)
        #pragma unroll
        for (int nt = 0; nt < 4; ++nt)
            acc[mt][nt] = (f32x4){0.f, 0.f, 0.f, 0.f};

    const unsigned short* aBase = Wcb + (size_t)m0 * 256;
    const unsigned short* bBase = xbt + ((size_t)b * HW + p0) * 256;

    for (int k0 = 0; k0 < 256; k0 += 32) {
        #pragma unroll
        for (int i = 0; i < 2; ++i) {
            int u = t + 256 * i;          // 512 tasks x 16B
            int row = u >> 2, sub = u & 3;
            *(int4*)(As + row * 32 + sub * 8) =
                *(const int4*)(aBase + (size_t)row * 256 + k0 + sub * 8);
            *(int4*)(Bs + row * 32 + sub * 8) =
                *(const int4*)(bBase + (size_t)row * 256 + k0 + sub * 8);
        }
        __syncthreads();
        bf16x8 af[4], bf[4];
        #pragma unroll
        for (int mt = 0; mt < 4; ++mt)
            af[mt] = *(const bf16x8*)(const void*)(As + (wm + mt * 16 + l15) * 32 + quad * 8);
        #pragma unroll
        for (int nt = 0; nt < 4; ++nt)
            bf[nt] = *(const bf16x8*)(const void*)(Bs + (wn + nt * 16 + l15) * 32 + quad * 8);
        #pragma unroll
        for (int mt = 0; mt < 4; ++mt)
            #pragma unroll
            for (int nt = 0; nt < 4; ++nt)
                acc[mt][nt] = __builtin_amdgcn_mfma_f32_16x16x32_bf16(af[mt], bf[nt], acc[mt][nt], 0, 0, 0);
        __syncthreads();
    }

    // epilogue: D row = quad*4+reg (o), col = l15 (p); + bias, cvt bf16
    #pragma unroll
    for (int mt = 0; mt < 4; ++mt) {
        int ob = m0 + wm + mt * 16 + quad * 4;
        #pragma unroll
        for (int reg = 0; reg < 4; ++reg) {
            int o = ob + reg;
            float bias = bc[o];
            unsigned short* dst = proj + ((size_t)b * 256 + o) * HW + p0 + wn + l15;
            #pragma unroll
            for (int nt = 0; nt < 4; ++nt)
                dst[nt * 16] = f2bf(acc[mt][nt][reg] + bias);
        }
    }
}

// ---------------------------------------------------------------------------
// Kernel 4: bilinear sample + softmax-weighted sum.
//   out[b][o][p] = sum over 16 (idx,w): proj[b][o][idx] * w
//   block: 64 p x 4 o-groups (one wave per group), 64 o-iters each.
// ---------------------------------------------------------------------------
extern "C" __global__ __launch_bounds__(256)
void sample_kernel(const unsigned short* __restrict__ proj,
                   const float2* __restrict__ coords,
                   const float* __restrict__ wts,
                   float* __restrict__ out)
{
    const int t  = threadIdx.x;
    const int bx = blockIdx.x;
    const int b  = bx / 144;
    const int p0 = (bx % 144) * 64;
    const int pl = t & 63, og = t >> 6;
    const int p  = p0 + pl;

    int   idx[16];
    float w[16];
    #pragma unroll
    for (int k = 0; k < NK; ++k) {
        float2 cc = coords[((size_t)k * NB + b) * HW + p];
        float wk  = wts[((size_t)k * NB + b) * HW + p];
        float x0f = floorf(cc.x), y0f = floorf(cc.y);
        float wx1 = cc.x - x0f, wx0 = 1.0f - wx1;
        float wy1 = cc.y - y0f, wy0 = 1.0f - wy1;
        int x0 = (int)x0f, y0 = (int)y0f;
        int x1 = x0 + 1,   y1 = y0 + 1;
        float vx0 = (x0 >= 0 && x0 < IMG) ? 1.f : 0.f;
        float vx1 = (x1 >= 0 && x1 < IMG) ? 1.f : 0.f;
        float vy0 = (y0 >= 0 && y0 < IMG) ? 1.f : 0.f;
        float vy1 = (y1 >= 0 && y1 < IMG) ? 1.f : 0.f;
        int cx0 = min(max(x0, 0), IMG - 1), cx1 = min(max(x1, 0), IMG - 1);
        int cy0 = min(max(y0, 0), IMG - 1), cy1 = min(max(y1, 0), IMG - 1);
        idx[k * 4 + 0] = cy0 * IMG + cx0;  w[k * 4 + 0] = wk * wx0 * wy0 * vx0 * vy0;
        idx[k * 4 + 1] = cy0 * IMG + cx1;  w[k * 4 + 1] = wk * wx1 * wy0 * vx1 * vy0;
        idx[k * 4 + 2] = cy1 * IMG + cx0;  w[k * 4 + 2] = wk * wx0 * wy1 * vx0 * vy1;
        idx[k * 4 + 3] = cy1 * IMG + cx1;  w[k * 4 + 3] = wk * wx1 * wy1 * vx1 * vy1;
    }

    const unsigned short* pr = proj + ((size_t)(b * 256 + og * 64)) * HW;
    float* po = out + ((size_t)(b * 256 + og * 64)) * HW + p;
    for (int oi = 0; oi < 64; ++oi) {
        float acc = 0.f;
        #pragma unroll
        for (int j = 0; j < 16; ++j)
            acc += w[j] * bf2f(pr[idx[j]]);
        *po = acc;
        pr += HW; po += HW;
    }
}

// ---------------------------------------------------------------------------
extern "C" void kernel_launch(void* const* d_in, const int* in_sizes, int n_in,
                              void* d_out, int out_size, void* d_ws, size_t ws_size,
                              hipStream_t stream)
{
    const float* x    = (const float*)d_in[0];
    const float* Wc   = (const float*)d_in[1];
    const float* bc   = (const float*)d_in[2];
    const float* Woff = (const float*)d_in[3];
    const float* boff = (const float*)d_in[4];
    const float* Wwt  = (const float*)d_in[5];
    const float* bwt  = (const float*)d_in[6];
    float* out = (float*)d_out;

    char* ws = (char*)d_ws;
    unsigned short* xbt  = (unsigned short*)(ws);               // 8*9216*256*2 = 37748736 B
    unsigned short* proj = (unsigned short*)(ws + 37748736);    // 37748736 B
    float2* coords       = (float2*)(ws + 75497472);            // 4*8*9216*8 = 2359296 B
    float*  wts          = (float*)(ws + 77856768);             // 4*8*9216*4 = 1179648 B
    unsigned short* Wcb  = (unsigned short*)(ws + 79036416);    // 131072 B  (total ~79.2 MB)

    prep_kernel<<<dim3(NB * 72), dim3(256), 0, stream>>>(x, Woff, boff, Wwt, bwt, xbt, coords, wts);
    wcconv_kernel<<<dim3(64), dim3(256), 0, stream>>>(Wc, Wcb);
    gemm_kernel<<<dim3(NB * 144), dim3(256), 0, stream>>>(Wcb, xbt, bc, proj);
    sample_kernel<<<dim3(NB * 144), dim3(256), 0, stream>>>(proj, coords, wts, out);
}

// Round 2
// 234.031 us; speedup vs baseline: 1.6425x; 1.6425x over previous
//
#include <hip/hip_runtime.h>

#define HW   9216
#define IMG  96
#define NB   8
#define NK   4

typedef __bf16 bf16x8 __attribute__((ext_vector_type(8)));
typedef float  f32x4  __attribute__((ext_vector_type(4)));

__device__ __forceinline__ unsigned short f2bf(float f) {
    unsigned int u = __float_as_uint(f);
    u += 0x7FFFu + ((u >> 16) & 1u);   // round-to-nearest-even (finite inputs)
    return (unsigned short)(u >> 16);
}
__device__ __forceinline__ float bf2f(unsigned short h) {
    return __uint_as_float(((unsigned int)h) << 16);
}

// ---------------------------------------------------------------------------
// Kernel 1: prep.  Per 64-pixel tile:
//   - x [b][c][hw] fp32 -> xbt [b][hw][c] bf16 (pixel-major, GEMM/sample layout)
//   - 12 dots/pixel (8 flow comps + 4 logits), fp32 exact -> coords + softmax wts
// block 256 = 4 c-strips x 64 px; grid NB*144. One barrier.
// ---------------------------------------------------------------------------
extern "C" __global__ __launch_bounds__(256)
void prep_kernel(const float* __restrict__ x,
                 const float* __restrict__ Woff,
                 const float* __restrict__ boff,
                 const float* __restrict__ Wwt,
                 const float* __restrict__ bwt,
                 unsigned short* __restrict__ xbt,
                 float2* __restrict__ coords,
                 float* __restrict__ wts)
{
    __shared__ unsigned short tile[64 * 264];   // [px][c] bf16, row stride 264
    __shared__ float red[4 * 64 * 13];          // [g][px][j] partial dots

    const int t  = threadIdx.x;
    const int b  = blockIdx.x / 144;
    const int p0 = (blockIdx.x % 144) * 64;
    const int px = t & 63;
    const int g  = __builtin_amdgcn_readfirstlane(t >> 6);  // wave-uniform strip id

    float acc[12];
    #pragma unroll
    for (int j = 0; j < 12; ++j) acc[j] = 0.f;

    const float* xb = x + ((size_t)(b * 256 + g * 64)) * HW + p0 + px;
    unsigned int* trow = (unsigned int*)tile;

    for (int i = 0; i < 64; i += 2) {
        const int c = g * 64 + i;
        float v0 = xb[(size_t)i * HW];          // coalesced: lanes = contiguous px
        float v1 = xb[(size_t)(i + 1) * HW];
        // 12 dot accumulations; weight addresses are wave-uniform -> scalar loads
        #pragma unroll
        for (int j = 0; j < 8; ++j)
            acc[j] += v0 * Woff[j * 256 + c] + v1 * Woff[j * 256 + c + 1];
        #pragma unroll
        for (int j = 0; j < 4; ++j)
            acc[8 + j] += v0 * Wwt[j * 256 + c] + v1 * Wwt[j * 256 + c + 1];
        // bf16 pair -> LDS [px][c]
        unsigned int pk = (unsigned int)f2bf(v0) | ((unsigned int)f2bf(v1) << 16);
        trow[px * 132 + (c >> 1)] = pk;
    }

    #pragma unroll
    for (int j = 0; j < 12; ++j)
        red[(g * 64 + px) * 13 + j] = acc[j];

    __syncthreads();

    // pack xbt: 64 px x 256 c bf16, int4 stores (lanes 0-31 = contiguous 512 B)
    #pragma unroll
    for (int r = 0; r < 8; ++r) {
        int u = t + 256 * r;
        int sub = u & 31, p2 = u >> 5;
        int4 v = *(const int4*)(tile + p2 * 264 + sub * 8);
        *(int4*)(xbt + ((size_t)b * HW + p0 + p2) * 256 + sub * 8) = v;
    }

    if (t < 64) {
        float s[12];
        #pragma unroll
        for (int j = 0; j < 12; ++j)
            s[j] = red[(0 * 64 + px) * 13 + j] + red[(1 * 64 + px) * 13 + j] +
                   red[(2 * 64 + px) * 13 + j] + red[(3 * 64 + px) * 13 + j];

        const int p = p0 + px;
        const float pyf = (float)(p / IMG);
        const float pxf = (float)(p % IMG);

        #pragma unroll
        for (int k = 0; k < NK; ++k) {
            float fx = s[k * 2 + 0] + boff[k * 2 + 0];
            float fy = s[k * 2 + 1] + boff[k * 2 + 1];
            float vx = 2.0f * (pxf + fx) / 95.0f - 1.0f;
            float vy = 2.0f * (pyf + fy) / 95.0f - 1.0f;
            float ix = (vx + 1.0f) * 48.0f - 0.5f;
            float iy = (vy + 1.0f) * 48.0f - 0.5f;
            coords[((size_t)k * NB + b) * HW + p] = make_float2(ix, iy);
        }
        float l0 = s[8] + bwt[0], l1 = s[9] + bwt[1];
        float l2 = s[10] + bwt[2], l3 = s[11] + bwt[3];
        float m = fmaxf(fmaxf(l0, l1), fmaxf(l2, l3));
        float e0 = __expf(l0 - m), e1 = __expf(l1 - m);
        float e2 = __expf(l2 - m), e3 = __expf(l3 - m);
        float inv = 1.0f / (e0 + e1 + e2 + e3);
        wts[((size_t)0 * NB + b) * HW + p] = e0 * inv;
        wts[((size_t)1 * NB + b) * HW + p] = e1 * inv;
        wts[((size_t)2 * NB + b) * HW + p] = e2 * inv;
        wts[((size_t)3 * NB + b) * HW + p] = e3 * inv;
    }
}

// ---------------------------------------------------------------------------
// Kernel 2: Wc fp32 -> bf16 (row-major [o][c], A-operand layout)
// ---------------------------------------------------------------------------
extern "C" __global__ __launch_bounds__(256)
void wcconv_kernel(const float* __restrict__ Wc, unsigned short* __restrict__ Wcb)
{
    int u = (blockIdx.x * 256 + threadIdx.x) * 4;
    float4 v = *(const float4*)(Wc + u);
    union { unsigned short h[4]; int2 p; } pk;
    pk.h[0] = f2bf(v.x); pk.h[1] = f2bf(v.y);
    pk.h[2] = f2bf(v.z); pk.h[3] = f2bf(v.w);
    *(int2*)(Wcb + u) = pk.p;
}

// ---------------------------------------------------------------------------
// Kernel 3: bilinear sample on x (pixel-major bf16), softmax-weighted:
//   xs[b][p][c] = sum_{16 corners} w_j(p) * xbt[b][idx_j(p)][c]
//   Also writes wsum[b][p] = sum_j w_j into the dead wts[k=0] slice.
// block 256 = 8 px x 32 c-chunks(8c); lanes sharing a pixel -> 512 B
// contiguous gather segments. grid NB*1152.
// ---------------------------------------------------------------------------
extern "C" __global__ __launch_bounds__(256)
void sample_kernel(const unsigned short* __restrict__ xbt,
                   const float2* __restrict__ coords,
                   float* __restrict__ wts,
                   unsigned short* __restrict__ xs)
{
    const int t  = threadIdx.x;
    const int b  = blockIdx.x / 1152;
    const int p0 = (blockIdx.x % 1152) * 8;
    const int pxl = t >> 5, ch = t & 31;
    const int p  = p0 + pxl;

    int   idx[16];
    float w[16];
    #pragma unroll
    for (int k = 0; k < NK; ++k) {
        float2 cc = coords[((size_t)k * NB + b) * HW + p];
        float wk  = wts[((size_t)k * NB + b) * HW + p];
        float x0f = floorf(cc.x), y0f = floorf(cc.y);
        float wx1 = cc.x - x0f, wx0 = 1.0f - wx1;
        float wy1 = cc.y - y0f, wy0 = 1.0f - wy1;
        int x0 = (int)x0f, y0 = (int)y0f;
        int x1 = x0 + 1,   y1 = y0 + 1;
        float vx0 = (x0 >= 0 && x0 < IMG) ? 1.f : 0.f;
        float vx1 = (x1 >= 0 && x1 < IMG) ? 1.f : 0.f;
        float vy0 = (y0 >= 0 && y0 < IMG) ? 1.f : 0.f;
        float vy1 = (y1 >= 0 && y1 < IMG) ? 1.f : 0.f;
        int cx0 = min(max(x0, 0), IMG - 1), cx1 = min(max(x1, 0), IMG - 1);
        int cy0 = min(max(y0, 0), IMG - 1), cy1 = min(max(y1, 0), IMG - 1);
        idx[k * 4 + 0] = cy0 * IMG + cx0;  w[k * 4 + 0] = wk * wx0 * wy0 * vx0 * vy0;
        idx[k * 4 + 1] = cy0 * IMG + cx1;  w[k * 4 + 1] = wk * wx1 * wy0 * vx1 * vy0;
        idx[k * 4 + 2] = cy1 * IMG + cx0;  w[k * 4 + 2] = wk * wx0 * wy1 * vx0 * vy1;
        idx[k * 4 + 3] = cy1 * IMG + cx1;  w[k * 4 + 3] = wk * wx1 * wy1 * vx1 * vy1;
    }

    const unsigned short* base = xbt + (size_t)b * HW * 256 + ch * 8;
    float acc[8];
    #pragma unroll
    for (int i = 0; i < 8; ++i) acc[i] = 0.f;

    #pragma unroll
    for (int j = 0; j < 16; ++j) {
        int4 v = *(const int4*)(base + (size_t)idx[j] * 256);
        const unsigned int* u = (const unsigned int*)&v;
        float wj = w[j];
        #pragma unroll
        for (int q = 0; q < 4; ++q) {
            float lo = __uint_as_float(u[q] << 16);
            float hi = __uint_as_float(u[q] & 0xFFFF0000u);
            acc[2 * q + 0] += wj * lo;
            acc[2 * q + 1] += wj * hi;
        }
    }

    union { unsigned short h[8]; int4 v; } pk;
    #pragma unroll
    for (int i = 0; i < 8; ++i) pk.h[i] = f2bf(acc[i]);
    *(int4*)(xs + ((size_t)b * HW + p) * 256 + ch * 8) = pk.v;

    if (ch == 0) {
        float wsum = 0.f;
        #pragma unroll
        for (int j = 0; j < 16; ++j) wsum += w[j];
        // dead k=0 slice; all reads of it happened earlier in this same wave
        wts[(size_t)b * HW + p] = wsum;
    }
}

// ---------------------------------------------------------------------------
// Kernel 4: bf16 MFMA GEMM: out[b][o][p] = sum_c Wc[o][c]*xs[b][p][c]
//                                        + bc[o]*wsum[b][p]   (fp32 out)
// 128x128 tile, BK=32, 4 waves x (4x4 of 16x16x32). grid NB*144.
// ---------------------------------------------------------------------------
extern "C" __global__ __launch_bounds__(256)
void gemm_kernel(const unsigned short* __restrict__ Wcb,
                 const unsigned short* __restrict__ xs,
                 const float* __restrict__ bc,
                 const float* __restrict__ wts,   // k=0 slice = wsum[b][p]
                 float* __restrict__ out)
{
    __shared__ __align__(16) unsigned short As[128 * 32];
    __shared__ __align__(16) unsigned short Bs[128 * 32];

    const int t  = threadIdx.x;
    const int bx = blockIdx.x;
    const int b  = bx / 144;
    const int r  = bx % 144;
    const int m0 = (r / 72) * 128;   // o tile
    const int p0 = (r % 72) * 128;   // p tile

    const int lane = t & 63, wave = t >> 6;
    const int wm = (wave >> 1) * 64, wn = (wave & 1) * 64;
    const int l15 = lane & 15, quad = lane >> 4;

    f32x4 acc[4][4];
    #pragma unroll
    for (int mt = 0; mt < 4; ++mt)
        #pragma unroll
        for (int nt = 0; nt < 4; ++nt)
            acc[mt][nt] = (f32x4){0.f, 0.f, 0.f, 0.f};

    const unsigned short* aBase = Wcb + (size_t)m0 * 256;
    const unsigned short* bBase = xs + ((size_t)b * HW + p0) * 256;

    for (int k0 = 0; k0 < 256; k0 += 32) {
        #pragma unroll
        for (int i = 0; i < 2; ++i) {
            int u = t + 256 * i;          // 512 tasks x 16B
            int row = u >> 2, sub = u & 3;
            *(int4*)(As + row * 32 + sub * 8) =
                *(const int4*)(aBase + (size_t)row * 256 + k0 + sub * 8);
            *(int4*)(Bs + row * 32 + sub * 8) =
                *(const int4*)(bBase + (size_t)row * 256 + k0 + sub * 8);
        }
        __syncthreads();
        bf16x8 af[4], bf[4];
        #pragma unroll
        for (int mt = 0; mt < 4; ++mt)
            af[mt] = *(const bf16x8*)(const void*)(As + (wm + mt * 16 + l15) * 32 + quad * 8);
        #pragma unroll
        for (int nt = 0; nt < 4; ++nt)
            bf[nt] = *(const bf16x8*)(const void*)(Bs + (wn + nt * 16 + l15) * 32 + quad * 8);
        #pragma unroll
        for (int mt = 0; mt < 4; ++mt)
            #pragma unroll
            for (int nt = 0; nt < 4; ++nt)
                acc[mt][nt] = __builtin_amdgcn_mfma_f32_16x16x32_bf16(af[mt], bf[nt], acc[mt][nt], 0, 0, 0);
        __syncthreads();
    }

    // wsum for this thread's 4 p-columns
    float wv[4];
    #pragma unroll
    for (int nt = 0; nt < 4; ++nt)
        wv[nt] = wts[(size_t)b * HW + p0 + wn + nt * 16 + l15];

    // epilogue: D row = quad*4+reg (o), col = l15 (p); fp32 out + bias*wsum
    #pragma unroll
    for (int mt = 0; mt < 4; ++mt) {
        int ob = m0 + wm + mt * 16 + quad * 4;
        #pragma unroll
        for (int reg = 0; reg < 4; ++reg) {
            int o = ob + reg;
            float bias = bc[o];
            float* dst = out + ((size_t)b * 256 + o) * HW + p0 + wn + l15;
            #pragma unroll
            for (int nt = 0; nt < 4; ++nt)
                dst[nt * 16] = acc[mt][nt][reg] + bias * wv[nt];
        }
    }
}

// ---------------------------------------------------------------------------
extern "C" void kernel_launch(void* const* d_in, const int* in_sizes, int n_in,
                              void* d_out, int out_size, void* d_ws, size_t ws_size,
                              hipStream_t stream)
{
    const float* x    = (const float*)d_in[0];
    const float* Wc   = (const float*)d_in[1];
    const float* bc   = (const float*)d_in[2];
    const float* Woff = (const float*)d_in[3];
    const float* boff = (const float*)d_in[4];
    const float* Wwt  = (const float*)d_in[5];
    const float* bwt  = (const float*)d_in[6];
    float* out = (float*)d_out;

    char* ws = (char*)d_ws;
    unsigned short* xbt  = (unsigned short*)(ws);               // 37748736 B
    unsigned short* xs   = (unsigned short*)(ws + 37748736);    // 37748736 B
    float2* coords       = (float2*)(ws + 75497472);            // 2359296 B
    float*  wts          = (float*)(ws + 77856768);             // 1179648 B
    unsigned short* Wcb  = (unsigned short*)(ws + 79036416);    // 131072 B

    prep_kernel<<<dim3(NB * 144), dim3(256), 0, stream>>>(x, Woff, boff, Wwt, bwt, xbt, coords, wts);
    wcconv_kernel<<<dim3(64), dim3(256), 0, stream>>>(Wc, Wcb);
    sample_kernel<<<dim3(NB * 1152), dim3(256), 0, stream>>>(xbt, coords, wts, xs);
    gemm_kernel<<<dim3(NB * 144), dim3(256), 0, stream>>>(Wcb, xs, bc, wts, out);
}

// Round 3
// 214.008 us; speedup vs baseline: 1.7961x; 1.0936x over previous
//
#include <hip/hip_runtime.h>

#define HW   9216
#define IMG  96
#define NB   8
#define NK   4

typedef __bf16 bf16x8 __attribute__((ext_vector_type(8)));
typedef float  f32x4  __attribute__((ext_vector_type(4)));

__device__ __forceinline__ unsigned short f2bf(float f) {
    unsigned int u = __float_as_uint(f);
    u += 0x7FFFu + ((u >> 16) & 1u);   // round-to-nearest-even (finite inputs)
    return (unsigned short)(u >> 16);
}

// ---------------------------------------------------------------------------
// Kernel 1: prep (+ folded Wc->bf16 conversion in trailing 64 blocks).
// Per 64-pixel tile:
//   - x [b][c][hw] fp32 -> xbt [b][hw][c] bf16 (pixel-major)
//   - 12 dots/pixel (8 flow comps + 4 logits), fp32 exact -> coords + softmax wts
// block 256 = 4 c-strips x 64 px. 8 loads in flight per iter (latency fix).
// red buffer aliases the transpose tile -> 34 KB LDS -> 4 blocks/CU.
// ---------------------------------------------------------------------------
extern "C" __global__ __launch_bounds__(256, 4)
void prep_kernel(const float* __restrict__ x,
                 const float* __restrict__ Wc,
                 const float* __restrict__ Woff,
                 const float* __restrict__ boff,
                 const float* __restrict__ Wwt,
                 const float* __restrict__ bwt,
                 unsigned short* __restrict__ xbt,
                 unsigned short* __restrict__ Wcb,
                 float2* __restrict__ coords,
                 float* __restrict__ wts)
{
    __shared__ __align__(16) unsigned short tile[64 * 264];   // 33792 B

    const int t   = threadIdx.x;
    const int bxr = blockIdx.x;

    if (bxr >= NB * 144) {
        // Wc fp32 -> bf16, row-major [o][c] (A-operand layout). 64 blocks.
        int u = ((bxr - NB * 144) * 256 + t) * 4;
        float4 v = *(const float4*)(Wc + u);
        union { unsigned short h[4]; int2 p; } pk;
        pk.h[0] = f2bf(v.x); pk.h[1] = f2bf(v.y);
        pk.h[2] = f2bf(v.z); pk.h[3] = f2bf(v.w);
        *(int2*)(Wcb + u) = pk.p;
        return;
    }

    const int b  = bxr / 144;
    const int p0 = (bxr % 144) * 64;
    const int px = t & 63;
    const int g  = __builtin_amdgcn_readfirstlane(t >> 6);  // wave-uniform strip

    float acc[12];
    #pragma unroll
    for (int j = 0; j < 12; ++j) acc[j] = 0.f;

    const float* xb = x + ((size_t)(b * 256 + g * 64)) * HW + p0 + px;
    unsigned int* trow = (unsigned int*)tile;

    for (int i0 = 0; i0 < 64; i0 += 8) {
        float v[8];
        #pragma unroll
        for (int q = 0; q < 8; ++q)
            v[q] = xb[(size_t)(i0 + q) * HW];     // 8 independent loads in flight
        #pragma unroll
        for (int q = 0; q < 8; ++q) {
            const int c = g * 64 + i0 + q;        // wave-uniform -> scalar wt loads
            #pragma unroll
            for (int j = 0; j < 8; ++j) acc[j] += v[q] * Woff[j * 256 + c];
            #pragma unroll
            for (int j = 0; j < 4; ++j) acc[8 + j] += v[q] * Wwt[j * 256 + c];
        }
        #pragma unroll
        for (int q = 0; q < 8; q += 2) {
            unsigned int pk = (unsigned int)f2bf(v[q]) | ((unsigned int)f2bf(v[q + 1]) << 16);
            trow[px * 132 + ((g * 64 + i0 + q) >> 1)] = pk;
        }
    }

    __syncthreads();
    // pack xbt: 64 px x 256 c bf16, int4 stores (lanes 0-31 = contiguous 512 B)
    #pragma unroll
    for (int r = 0; r < 8; ++r) {
        int u = t + 256 * r;
        int sub = u & 31, p2 = u >> 5;
        int4 v = *(const int4*)(tile + p2 * 264 + sub * 8);
        *(int4*)(xbt + ((size_t)b * HW + p0 + p2) * 256 + sub * 8) = v;
    }
    __syncthreads();

    // cross-wave partial-dot reduction through re-used tile memory (12288 B)
    float* red = (float*)tile;
    #pragma unroll
    for (int j = 0; j < 12; ++j)
        red[(g * 64 + px) * 12 + j] = acc[j];
    __syncthreads();

    if (t < 64) {
        float s[12];
        #pragma unroll
        for (int j = 0; j < 12; ++j)
            s[j] = red[(0 * 64 + px) * 12 + j] + red[(1 * 64 + px) * 12 + j] +
                   red[(2 * 64 + px) * 12 + j] + red[(3 * 64 + px) * 12 + j];

        const int p = p0 + px;
        const float pyf = (float)(p / IMG);
        const float pxf = (float)(p % IMG);

        #pragma unroll
        for (int k = 0; k < NK; ++k) {
            float fx = s[k * 2 + 0] + boff[k * 2 + 0];
            float fy = s[k * 2 + 1] + boff[k * 2 + 1];
            float vx = 2.0f * (pxf + fx) / 95.0f - 1.0f;
            float vy = 2.0f * (pyf + fy) / 95.0f - 1.0f;
            float ix = (vx + 1.0f) * 48.0f - 0.5f;
            float iy = (vy + 1.0f) * 48.0f - 0.5f;
            coords[((size_t)k * NB + b) * HW + p] = make_float2(ix, iy);
        }
        float l0 = s[8] + bwt[0], l1 = s[9] + bwt[1];
        float l2 = s[10] + bwt[2], l3 = s[11] + bwt[3];
        float m = fmaxf(fmaxf(l0, l1), fmaxf(l2, l3));
        float e0 = __expf(l0 - m), e1 = __expf(l1 - m);
        float e2 = __expf(l2 - m), e3 = __expf(l3 - m);
        float inv = 1.0f / (e0 + e1 + e2 + e3);
        wts[((size_t)0 * NB + b) * HW + p] = e0 * inv;
        wts[((size_t)1 * NB + b) * HW + p] = e1 * inv;
        wts[((size_t)2 * NB + b) * HW + p] = e2 * inv;
        wts[((size_t)3 * NB + b) * HW + p] = e3 * inv;
    }
}

// ---------------------------------------------------------------------------
// Kernel 2: bilinear sample on x (pixel-major bf16), softmax-weighted:
//   xs[b][p][c] = sum_{16 corners} w_j(p) * xbt[b][idx_j(p)][c]
//   Also writes wsum[b][p] = sum_j w_j into the dead wts[k=0] slice.
// block 256 = 8 px x 32 c-chunks(8c). grid NB*1152.
// ---------------------------------------------------------------------------
extern "C" __global__ __launch_bounds__(256)
void sample_kernel(const unsigned short* __restrict__ xbt,
                   const float2* __restrict__ coords,
                   float* __restrict__ wts,
                   unsigned short* __restrict__ xs)
{
    const int t  = threadIdx.x;
    const int b  = blockIdx.x / 1152;
    const int p0 = (blockIdx.x % 1152) * 8;
    const int pxl = t >> 5, ch = t & 31;
    const int p  = p0 + pxl;

    int   idx[16];
    float w[16];
    #pragma unroll
    for (int k = 0; k < NK; ++k) {
        float2 cc = coords[((size_t)k * NB + b) * HW + p];
        float wk  = wts[((size_t)k * NB + b) * HW + p];
        float x0f = floorf(cc.x), y0f = floorf(cc.y);
        float wx1 = cc.x - x0f, wx0 = 1.0f - wx1;
        float wy1 = cc.y - y0f, wy0 = 1.0f - wy1;
        int x0 = (int)x0f, y0 = (int)y0f;
        int x1 = x0 + 1,   y1 = y0 + 1;
        float vx0 = (x0 >= 0 && x0 < IMG) ? 1.f : 0.f;
        float vx1 = (x1 >= 0 && x1 < IMG) ? 1.f : 0.f;
        float vy0 = (y0 >= 0 && y0 < IMG) ? 1.f : 0.f;
        float vy1 = (y1 >= 0 && y1 < IMG) ? 1.f : 0.f;
        int cx0 = min(max(x0, 0), IMG - 1), cx1 = min(max(x1, 0), IMG - 1);
        int cy0 = min(max(y0, 0), IMG - 1), cy1 = min(max(y1, 0), IMG - 1);
        idx[k * 4 + 0] = cy0 * IMG + cx0;  w[k * 4 + 0] = wk * wx0 * wy0 * vx0 * vy0;
        idx[k * 4 + 1] = cy0 * IMG + cx1;  w[k * 4 + 1] = wk * wx1 * wy0 * vx1 * vy0;
        idx[k * 4 + 2] = cy1 * IMG + cx0;  w[k * 4 + 2] = wk * wx0 * wy1 * vx0 * vy1;
        idx[k * 4 + 3] = cy1 * IMG + cx1;  w[k * 4 + 3] = wk * wx1 * wy1 * vx1 * vy1;
    }

    const unsigned short* base = xbt + (size_t)b * HW * 256 + ch * 8;
    float acc[8];
    #pragma unroll
    for (int i = 0; i < 8; ++i) acc[i] = 0.f;

    #pragma unroll
    for (int j = 0; j < 16; ++j) {
        int4 v = *(const int4*)(base + (size_t)idx[j] * 256);
        const unsigned int* u = (const unsigned int*)&v;
        float wj = w[j];
        #pragma unroll
        for (int q = 0; q < 4; ++q) {
            float lo = __uint_as_float(u[q] << 16);
            float hi = __uint_as_float(u[q] & 0xFFFF0000u);
            acc[2 * q + 0] += wj * lo;
            acc[2 * q + 1] += wj * hi;
        }
    }

    union { unsigned short h[8]; int4 v; } pk;
    #pragma unroll
    for (int i = 0; i < 8; ++i) pk.h[i] = f2bf(acc[i]);
    *(int4*)(xs + ((size_t)b * HW + p) * 256 + ch * 8) = pk.v;

    if (ch == 0) {
        float wsum = 0.f;
        #pragma unroll
        for (int j = 0; j < 16; ++j) wsum += w[j];
        // dead k=0 slice; all reads of it happened earlier in this same wave
        wts[(size_t)b * HW + p] = wsum;
    }
}

// ---------------------------------------------------------------------------
// Kernel 3: bf16 MFMA GEMM: out[b][o][p] = sum_c Wc[o][c]*xs[b][p][c]
//                                        + bc[o]*wsum[b][p]   (fp32 out)
// 128x128 tile, BK=32, 4 waves x (4x4 of 16x16x32).
// Staging via global_load_lds width=16 (LDS dest = wave base + lane*16B).
// ---------------------------------------------------------------------------
extern "C" __global__ __launch_bounds__(256)
void gemm_kernel(const unsigned short* __restrict__ Wcb,
                 const unsigned short* __restrict__ xs,
                 const float* __restrict__ bc,
                 const float* __restrict__ wts,   // k=0 slice = wsum[b][p]
                 float* __restrict__ out)
{
    __shared__ __align__(16) unsigned short As[128 * 32];
    __shared__ __align__(16) unsigned short Bs[128 * 32];

    const int t  = threadIdx.x;
    const int bx = blockIdx.x;
    const int b  = bx / 144;
    const int r  = bx % 144;
    const int m0 = (r / 72) * 128;   // o tile
    const int p0 = (r % 72) * 128;   // p tile

    const int lane = t & 63, wave = t >> 6;
    const int wm = (wave >> 1) * 64, wn = (wave & 1) * 64;
    const int l15 = lane & 15, quad = lane >> 4;

    f32x4 acc[4][4];
    #pragma unroll
    for (int mt = 0; mt < 4; ++mt)
        #pragma unroll
        for (int nt = 0; nt < 4; ++nt)
            acc[mt][nt] = (f32x4){0.f, 0.f, 0.f, 0.f};

    const unsigned short* aBase = Wcb + (size_t)m0 * 256;
    const unsigned short* bBase = xs + ((size_t)b * HW + p0) * 256;

    for (int k0 = 0; k0 < 256; k0 += 32) {
        #pragma unroll
        for (int i = 0; i < 2; ++i) {
            int u = t + 256 * i;          // 512 tasks x 16B; LDS = wave base + lane*16
            int row = u >> 2, sub = u & 3;
            __builtin_amdgcn_global_load_lds(
                (const __attribute__((address_space(1))) void*)(aBase + (size_t)row * 256 + k0 + sub * 8),
                (__attribute__((address_space(3))) void*)(As + u * 8), 16, 0, 0);
            __builtin_amdgcn_global_load_lds(
                (const __attribute__((address_space(1))) void*)(bBase + (size_t)row * 256 + k0 + sub * 8),
                (__attribute__((address_space(3))) void*)(Bs + u * 8), 16, 0, 0);
        }
        __syncthreads();
        bf16x8 af[4], bf[4];
        #pragma unroll
        for (int mt = 0; mt < 4; ++mt)
            af[mt] = *(const bf16x8*)(const void*)(As + (wm + mt * 16 + l15) * 32 + quad * 8);
        #pragma unroll
        for (int nt = 0; nt < 4; ++nt)
            bf[nt] = *(const bf16x8*)(const void*)(Bs + (wn + nt * 16 + l15) * 32 + quad * 8);
        #pragma unroll
        for (int mt = 0; mt < 4; ++mt)
            #pragma unroll
            for (int nt = 0; nt < 4; ++nt)
                acc[mt][nt] = __builtin_amdgcn_mfma_f32_16x16x32_bf16(af[mt], bf[nt], acc[mt][nt], 0, 0, 0);
        __syncthreads();
    }

    // wsum for this thread's 4 p-columns
    float wv[4];
    #pragma unroll
    for (int nt = 0; nt < 4; ++nt)
        wv[nt] = wts[(size_t)b * HW + p0 + wn + nt * 16 + l15];

    // epilogue: D row = quad*4+reg (o), col = l15 (p); fp32 out + bias*wsum
    #pragma unroll
    for (int mt = 0; mt < 4; ++mt) {
        int ob = m0 + wm + mt * 16 + quad * 4;
        #pragma unroll
        for (int reg = 0; reg < 4; ++reg) {
            int o = ob + reg;
            float bias = bc[o];
            float* dst = out + ((size_t)b * 256 + o) * HW + p0 + wn + l15;
            #pragma unroll
            for (int nt = 0; nt < 4; ++nt)
                dst[nt * 16] = acc[mt][nt][reg] + bias * wv[nt];
        }
    }
}

// ---------------------------------------------------------------------------
extern "C" void kernel_launch(void* const* d_in, const int* in_sizes, int n_in,
                              void* d_out, int out_size, void* d_ws, size_t ws_size,
                              hipStream_t stream)
{
    const float* x    = (const float*)d_in[0];
    const float* Wc   = (const float*)d_in[1];
    const float* bc   = (const float*)d_in[2];
    const float* Woff = (const float*)d_in[3];
    const float* boff = (const float*)d_in[4];
    const float* Wwt  = (const float*)d_in[5];
    const float* bwt  = (const float*)d_in[6];
    float* out = (float*)d_out;

    char* ws = (char*)d_ws;
    unsigned short* xbt  = (unsigned short*)(ws);               // 37748736 B
    unsigned short* xs   = (unsigned short*)(ws + 37748736);    // 37748736 B
    float2* coords       = (float2*)(ws + 75497472);            // 2359296 B
    float*  wts          = (float*)(ws + 77856768);             // 1179648 B
    unsigned short* Wcb  = (unsigned short*)(ws + 79036416);    // 131072 B

    prep_kernel<<<dim3(NB * 144 + 64), dim3(256), 0, stream>>>(
        x, Wc, Woff, boff, Wwt, bwt, xbt, Wcb, coords, wts);
    sample_kernel<<<dim3(NB * 1152), dim3(256), 0, stream>>>(xbt, coords, wts, xs);
    gemm_kernel<<<dim3(NB * 144), dim3(256), 0, stream>>>(Wcb, xs, bc, wts, out);
}